// Round 9
// baseline (144.304 us; speedup 1.0000x reference)
//
#include <hip/hip_runtime.h>

#define HH 224
#define WW 224
#define PSD 112
#define NP 12544      // 112*112 patches per plane
#define NBG 1024      // B*G
#define NCH 28        // 4-patch chunks per patch row
#define NTASK (112 * NCH)   // 3136 tasks per plane = 49 * 64 exactly
#define NITER 49

// upper-triangle pair enumeration, row-major: k -> (PI[k], PJ[k]), i<=j
constexpr int PI[45] = {0,0,0,0,0,0,0,0,0, 1,1,1,1,1,1,1,1, 2,2,2,2,2,2,2,
                        3,3,3,3,3,3, 4,4,4,4,4, 5,5,5,5, 6,6,6, 7,7, 8};
constexpr int PJ[45] = {0,1,2,3,4,5,6,7,8, 1,2,3,4,5,6,7,8, 2,3,4,5,6,7,8,
                        3,4,5,6,7,8, 4,5,6,7,8, 5,6,7,8, 6,7,8, 7,8, 8};

// Load L[0..8] = x[r][8t-1 .. 8t+7] (r assumed >= 0)
__device__ __forceinline__ void load_row9(const float* __restrict__ row,
                                          int t, float* L) {
    const int cb = 8 * t;
    L[0] = (t == 0) ? 0.f : row[cb - 1];
    float4 a = *reinterpret_cast<const float4*>(row + cb);
    float4 b = *reinterpret_cast<const float4*>(row + cb + 4);
    L[1] = a.x; L[2] = a.y; L[3] = a.z; L[4] = a.w;
    L[5] = b.x; L[6] = b.y; L[7] = b.z; L[8] = b.w;
}

// Accumulate this wave's quarter of the 54 gram outputs for one 4-patch task.
// All indices constant-fold after unrolling -> acc stays in registers.
template <int K0>
__device__ __forceinline__ void accum_q(float (&acc)[14],
                                        const float (&L)[3][9]) {
#pragma unroll
    for (int m = 0; m < 14; ++m) {
        const int k = K0 + m;
        if (k < 45) {
            const int i = PI[k], j = PJ[k];
            const int ir = i / 3, ic = i % 3, jr = j / 3, jc = j % 3;
#pragma unroll
            for (int u = 0; u < 4; ++u)
                acc[m] += L[ir][2 * u + ic] * L[jr][2 * u + jc];
        } else if (k < 54) {
            const int e = k - 45, er = e / 3, ec = e % 3;
#pragma unroll
            for (int u = 0; u < 4; ++u) acc[m] += L[er][2 * u + ec];
        }
    }
}

template <int K0>
__device__ __forceinline__ void reduce_q(float (&acc)[14], int lane,
                                         float* __restrict__ sh) {
#pragma unroll
    for (int m = 0; m < 14; ++m) {
        const int k = K0 + m;
        if (k < 54) {
            float v = acc[m];
            v += __shfl_down(v, 32, 64);
            v += __shfl_down(v, 16, 64);
            v += __shfl_down(v, 8, 64);
            v += __shfl_down(v, 4, 64);
            v += __shfl_down(v, 2, 64);
            v += __shfl_down(v, 1, 64);
            if (lane == 0) sh[k] = v;
        }
    }
}

__global__ __launch_bounds__(256, 4) void scann_k(
    const float* __restrict__ x,
    const float* __restrict__ Wq, const float* __restrict__ bq,
    const float* __restrict__ Wk, const float* __restrict__ bk,
    const float* __restrict__ Wv, const float* __restrict__ bv,
    const float* __restrict__ Wo, const float* __restrict__ bo,
    float* __restrict__ out) {
    const int bg = blockIdx.x;
    const int g = bg & 63;
    const float* __restrict__ xp = x + (size_t)bg * (HH * WW);
    const int tid = threadIdx.x;
    const int lane = tid & 63;
    const int wv = tid >> 6;

    __shared__ float sh[54];     // gram: 45 upper-tri products + 9 sums
    __shared__ float TT[81];
    __shared__ float Qm_s[9];
    __shared__ float wsh[81];
    __shared__ float cf[10];

    // ---- Phase 1: gram. All 4 waves sweep the SAME 64 tasks per iteration
    // (waves 2-4 L1-hit), each accumulating its 14-output quarter; a raw
    // s_barrier per iteration keeps waves in lockstep (locality only — no
    // cross-wave data deps, so no waitcnt drain needed).
    float acc[14];
#pragma unroll
    for (int m = 0; m < 14; ++m) acc[m] = 0.f;

    for (int q = 0; q < NITER; ++q) {
        const int task = q * 64 + lane;
        const int ph = task / NCH;
        const int t = task - ph * NCH;
        const int r0 = 2 * ph - 1;
        float L[3][9];
        if (r0 < 0) {
#pragma unroll
            for (int j = 0; j < 9; ++j) L[0][j] = 0.f;
        } else {
            load_row9(xp + r0 * WW, t, L[0]);
        }
        load_row9(xp + (r0 + 1) * WW, t, L[1]);
        load_row9(xp + (r0 + 2) * WW, t, L[2]);

        if (wv == 0)      accum_q<0>(acc, L);
        else if (wv == 1) accum_q<14>(acc, L);
        else if (wv == 2) accum_q<28>(acc, L);
        else              accum_q<42>(acc, L);
        __builtin_amdgcn_s_barrier();
    }

    // ---- Phase 2: per-wave shuffle reduce, direct sh[] write ----
    if (wv == 0)      reduce_q<0>(acc, lane, sh);
    else if (wv == 1) reduce_q<14>(acc, lane, sh);
    else if (wv == 2) reduce_q<28>(acc, lane, sh);
    else              reduce_q<42>(acc, lane, sh);
    __syncthreads();

    // ---- Phase 3: attention-weight solve (9 threads) ----
#define MIDX(i, j) (9 * (i) - (i) * ((i)-1) / 2 + ((j) - (i)))
#define MAT(i, j) ((i) <= (j) ? sh[MIDX(i, j)] : sh[MIDX(j, i)])
    if (tid < 9) {
        const int t = tid;
        const float* wqt = Wq + g * 81 + t * 9;
        float w[9];
#pragma unroll
        for (int j = 0; j < 9; ++j) w[j] = wqt[j];
        float q = 0.f;
#pragma unroll
        for (int j = 0; j < 9; ++j) q += w[j] * sh[45 + j];
        Qm_s[t] = q;
#pragma unroll
        for (int i = 0; i < 9; ++i) {
            float s = 0.f;
#pragma unroll
            for (int j = 0; j < 9; ++j) s += MAT(i, j) * w[j];
            TT[i * 9 + t] = s;
        }
    }
    __syncthreads();
    if (tid < 9) {
        const int s = tid;
        const float* wks = Wk + g * 81 + s * 9;
        float w[9];
#pragma unroll
        for (int i = 0; i < 9; ++i) w[i] = wks[i];
        float Km = 0.f;
#pragma unroll
        for (int i = 0; i < 9; ++i) Km += w[i] * sh[45 + i];
        const float bks = bk[g * 9 + s];
        float e[9];
#pragma unroll
        for (int t = 0; t < 9; ++t) {
            const float bqt = bq[g * 9 + t];
            float sum = bks * Qm_s[t] + bqt * Km + 12544.f * bks * bqt;
#pragma unroll
            for (int i = 0; i < 9; ++i) sum += w[i] * TT[i * 9 + t];
            e[t] = sum;
        }
        float mx = e[0];
#pragma unroll
        for (int t = 1; t < 9; ++t) mx = fmaxf(mx, e[t]);
        float ex[9], se = 0.f;
#pragma unroll
        for (int t = 0; t < 9; ++t) {
            ex[t] = expf(e[t] - mx);
            se += ex[t];
        }
        const float wos = Wo[g * 9 + s] / se;
#pragma unroll
        for (int t = 0; t < 9; ++t) wsh[s * 9 + t] = wos * ex[t];
    }
    __syncthreads();
    if (tid < 9) {
        const int j = tid;
        float weff[9];
#pragma unroll
        for (int t = 0; t < 9; ++t) {
            float s = 0.f;
#pragma unroll
            for (int s2 = 0; s2 < 9; ++s2) s += wsh[s2 * 9 + t];
            weff[t] = s;
        }
        float cj = 0.f;
#pragma unroll
        for (int t = 0; t < 9; ++t) cj += weff[t] * Wv[g * 81 + t * 9 + j];
        cf[j] = cj;
        if (j == 0) {
            float d = bo[g];
#pragma unroll
            for (int t = 0; t < 9; ++t) d += weff[t] * bv[g * 9 + t];
            cf[9] = d;
        }
    }
    __syncthreads();

    // ---- Phase 4: 3x3 stride-2 conv (thread-per-task, register-light) ----
    float cc[9];
#pragma unroll
    for (int j = 0; j < 9; ++j) cc[j] = cf[j];
    const float dd = cf[9];
    float* __restrict__ op = out + (size_t)bg * NP;

    for (int task = tid; task < NTASK; task += 256) {
        const int ph = task / NCH;
        const int t = task - ph * NCH;
        const int r0 = 2 * ph - 1;
        float L[3][9];
#pragma unroll
        for (int kr = 0; kr < 3; ++kr) {
            const int r = r0 + kr;
            if (r < 0) {
#pragma unroll
                for (int j = 0; j < 9; ++j) L[kr][j] = 0.f;
            } else {
                load_row9(xp + r * WW, t, L[kr]);
            }
        }
        float o[4];
#pragma unroll
        for (int u = 0; u < 4; ++u) {
            float s = dd;
#pragma unroll
            for (int kh = 0; kh < 3; ++kh)
#pragma unroll
                for (int kw = 0; kw < 3; ++kw)
                    s += cc[3 * kh + kw] * L[kh][2 * u + kw];
            o[u] = s;
        }
        *reinterpret_cast<float4*>(op + ph * PSD + 4 * t) =
            make_float4(o[0], o[1], o[2], o[3]);
    }
}

extern "C" void kernel_launch(void* const* d_in, const int* in_sizes, int n_in,
                              void* d_out, int out_size, void* d_ws, size_t ws_size,
                              hipStream_t stream) {
    const float* x = (const float*)d_in[0];
    const float* Wq = (const float*)d_in[1];
    const float* bq = (const float*)d_in[2];
    const float* Wk = (const float*)d_in[3];
    const float* bk = (const float*)d_in[4];
    const float* Wv = (const float*)d_in[5];
    const float* bv = (const float*)d_in[6];
    const float* Wo = (const float*)d_in[7];
    const float* bo = (const float*)d_in[8];
    float* out = (float*)d_out;

    scann_k<<<NBG, 256, 0, stream>>>(x, Wq, bq, Wk, bk, Wv, bv, Wo, bo, out);
}

// Round 10
// 99.039 us; speedup vs baseline: 1.4570x; 1.4570x over previous
//
#include <hip/hip_runtime.h>

#define HH 224
#define WW 224
#define PSD 112
#define NP 12544      // 112*112 patches per plane
#define NBG 1024      // B*G
#define NCH 28        // 4-patch chunks per patch row
#define NTASK (112 * NCH)   // 3136 = 49 chunks of 64
#define NCHUNK 49
#define BLK 512       // 8 waves: 4x role A + 4x role B; 64 VGPR -> 32 waves/CU

// upper-triangle pair enumeration, row-major: k -> (PI[k], PJ[k]), i<=j
constexpr int PI[45] = {0,0,0,0,0,0,0,0,0, 1,1,1,1,1,1,1,1, 2,2,2,2,2,2,2,
                        3,3,3,3,3,3, 4,4,4,4,4, 5,5,5,5, 6,6,6, 7,7, 8};
constexpr int PJ[45] = {0,1,2,3,4,5,6,7,8, 1,2,3,4,5,6,7,8, 2,3,4,5,6,7,8,
                        3,4,5,6,7,8, 4,5,6,7,8, 5,6,7,8, 6,7,8, 7,8, 8};

// Role A: products with i,j in {0..5} (window rows 0,1 only) + sums s0..s5.
// Role B: everything touching window row 2 + sums s6..s8.  27 outputs each.
constexpr int A_KS[27] = {0,1,2,3,4,5, 9,10,11,12,13, 17,18,19,20, 24,25,26,
                          30,31, 35, 45,46,47,48,49,50};
constexpr int B_KS[27] = {6,7,8, 14,15,16, 21,22,23, 27,28,29, 32,33,34,
                          36,37,38,39,40,41,42,43,44, 51,52,53};
// per flat output k: owning role and index within that role's acc[]
constexpr int ROLE_OF[54] = {0,0,0,0,0,0,1,1,1, 0,0,0,0,0,1,1,1, 0,0,0,0,1,1,1,
                             0,0,0,1,1,1, 0,0,1,1,1, 0,1,1,1, 1,1,1, 1,1, 1,
                             0,0,0,0,0,0, 1,1,1};
constexpr int INV_OF[54]  = {0,1,2,3,4,5,0,1,2, 6,7,8,9,10,3,4,5, 11,12,13,14,6,7,8,
                             15,16,17,9,10,11, 18,19,12,13,14, 20,15,16,17, 18,19,20,
                             21,22, 23, 21,22,23,24,25,26, 24,25,26};

// Load L[0..8] = x[r][8t-1 .. 8t+7] (r assumed >= 0)
__device__ __forceinline__ void load_row9(const float* __restrict__ row,
                                          int t, float* L) {
    const int cb = 8 * t;
    L[0] = (t == 0) ? 0.f : row[cb - 1];
    float4 a = *reinterpret_cast<const float4*>(row + cb);
    float4 b = *reinterpret_cast<const float4*>(row + cb + 4);
    L[1] = a.x; L[2] = a.y; L[3] = a.z; L[4] = a.w;
    L[5] = b.x; L[6] = b.y; L[7] = b.z; L[8] = b.w;
}

// Accumulate this role's 27 outputs for one 4-patch window.
// All indices constant-fold after unrolling (proven: R9 -> VGPR 40, no spill).
// Role 0 statically never references L[2].
template <int R>
__device__ __forceinline__ void accum_role(float (&acc)[27],
                                           const float (&L)[3][9]) {
#pragma unroll
    for (int m = 0; m < 27; ++m) {
        const int k = (R == 0) ? A_KS[m] : B_KS[m];
        if (k < 45) {
            const int i = PI[k], j = PJ[k];
            const int ir = i / 3, ic = i % 3, jr = j / 3, jc = j % 3;
#pragma unroll
            for (int u = 0; u < 4; ++u)
                acc[m] += L[ir][2 * u + ic] * L[jr][2 * u + jc];
        } else {
            const int e = k - 45, er = e / 3, ec = e % 3;
#pragma unroll
            for (int u = 0; u < 4; ++u) acc[m] += L[er][2 * u + ec];
        }
    }
}

__global__ __launch_bounds__(BLK) void scann_k(
    const float* __restrict__ x,
    const float* __restrict__ Wq, const float* __restrict__ bq,
    const float* __restrict__ Wk, const float* __restrict__ bk,
    const float* __restrict__ Wv, const float* __restrict__ bv,
    const float* __restrict__ Wo, const float* __restrict__ bo,
    float* __restrict__ out) {
    const int bg = blockIdx.x;
    const int g = bg & 63;
    const float* __restrict__ xp = x + (size_t)bg * (HH * WW);
    const int tid = threadIdx.x;
    const int lane = tid & 63;
    const int wv = tid >> 6;      // 0..7
    const int sub = wv & 3;       // chunk sub-index within the 256-task window
    const int role = wv >> 2;     // 0 = A (waves 0-3), 1 = B (waves 4-7)

    __shared__ float red[8][28];
    __shared__ float sh[54];
    __shared__ float TT[81];
    __shared__ float Qm_s[9];
    __shared__ float wsh[81];
    __shared__ float cf[10];

    // ---- Phase 1: gram. Waves w and w+4 process IDENTICAL tasks each iter
    // (role A needs window rows 0,1; role B rows 0,1,2) -> second role's loads
    // hit L1/L2. Barrier per iter bounds drift. 13 uniform iters, chunk-
    // granular validity (multiples of 64) -> no lane divergence, barrier-safe.
    float acc[27];
#pragma unroll
    for (int m = 0; m < 27; ++m) acc[m] = 0.f;

    for (int it = 0; it < 13; ++it) {
        const int chunk = it * 4 + sub;
        if (chunk < NCHUNK) {
            const int task = chunk * 64 + lane;
            const int ph = task / NCH;
            const int t = task - ph * NCH;
            const int r0 = 2 * ph - 1;
            if (role == 0) {
                float L[3][9];
                if (r0 < 0) {
#pragma unroll
                    for (int j = 0; j < 9; ++j) L[0][j] = 0.f;
                } else {
                    load_row9(xp + r0 * WW, t, L[0]);
                }
                load_row9(xp + (r0 + 1) * WW, t, L[1]);
                accum_role<0>(acc, L);
            } else {
                float L[3][9];
                if (r0 < 0) {
#pragma unroll
                    for (int j = 0; j < 9; ++j) L[0][j] = 0.f;
                } else {
                    load_row9(xp + r0 * WW, t, L[0]);
                }
                load_row9(xp + (r0 + 1) * WW, t, L[1]);
                load_row9(xp + (r0 + 2) * WW, t, L[2]);
                accum_role<1>(acc, L);
            }
        }
        __builtin_amdgcn_s_barrier();
    }

    // ---- Phase 2: per-wave shuffle reduce, role-aware combine ----
#pragma unroll
    for (int m = 0; m < 27; ++m) {
        float v = acc[m];
        v += __shfl_down(v, 32, 64);
        v += __shfl_down(v, 16, 64);
        v += __shfl_down(v, 8, 64);
        v += __shfl_down(v, 4, 64);
        v += __shfl_down(v, 2, 64);
        v += __shfl_down(v, 1, 64);
        if (lane == 0) red[wv][m] = v;
    }
    __syncthreads();
    if (tid < 54) {
        const int w0 = ROLE_OF[tid] * 4;
        const int m = INV_OF[tid];
        sh[tid] = red[w0][m] + red[w0 + 1][m] + red[w0 + 2][m] + red[w0 + 3][m];
    }
    __syncthreads();

    // ---- Phase 3: attention-weight solve (9 threads) ----
#define MIDX(i, j) (9 * (i) - (i) * ((i)-1) / 2 + ((j) - (i)))
#define MAT(i, j) ((i) <= (j) ? sh[MIDX(i, j)] : sh[MIDX(j, i)])
    if (tid < 9) {
        const int t = tid;
        const float* wqt = Wq + g * 81 + t * 9;
        float w[9];
#pragma unroll
        for (int j = 0; j < 9; ++j) w[j] = wqt[j];
        float q = 0.f;
#pragma unroll
        for (int j = 0; j < 9; ++j) q += w[j] * sh[45 + j];
        Qm_s[t] = q;
#pragma unroll
        for (int i = 0; i < 9; ++i) {
            float s = 0.f;
#pragma unroll
            for (int j = 0; j < 9; ++j) s += MAT(i, j) * w[j];
            TT[i * 9 + t] = s;
        }
    }
    __syncthreads();
    if (tid < 9) {
        const int s = tid;
        const float* wks = Wk + g * 81 + s * 9;
        float w[9];
#pragma unroll
        for (int i = 0; i < 9; ++i) w[i] = wks[i];
        float Km = 0.f;
#pragma unroll
        for (int i = 0; i < 9; ++i) Km += w[i] * sh[45 + i];
        const float bks = bk[g * 9 + s];
        float e[9];
#pragma unroll
        for (int t = 0; t < 9; ++t) {
            const float bqt = bq[g * 9 + t];
            float sum = bks * Qm_s[t] + bqt * Km + 12544.f * bks * bqt;
#pragma unroll
            for (int i = 0; i < 9; ++i) sum += w[i] * TT[i * 9 + t];
            e[t] = sum;
        }
        float mx = e[0];
#pragma unroll
        for (int t = 1; t < 9; ++t) mx = fmaxf(mx, e[t]);
        float ex[9], se = 0.f;
#pragma unroll
        for (int t = 0; t < 9; ++t) {
            ex[t] = expf(e[t] - mx);
            se += ex[t];
        }
        const float wos = Wo[g * 9 + s] / se;
#pragma unroll
        for (int t = 0; t < 9; ++t) wsh[s * 9 + t] = wos * ex[t];
    }
    __syncthreads();
    if (tid < 9) {
        const int j = tid;
        float weff[9];
#pragma unroll
        for (int t = 0; t < 9; ++t) {
            float s = 0.f;
#pragma unroll
            for (int s2 = 0; s2 < 9; ++s2) s += wsh[s2 * 9 + t];
            weff[t] = s;
        }
        float cj = 0.f;
#pragma unroll
        for (int t = 0; t < 9; ++t) cj += weff[t] * Wv[g * 81 + t * 9 + j];
        cf[j] = cj;
        if (j == 0) {
            float d = bo[g];
#pragma unroll
            for (int t = 0; t < 9; ++t) d += weff[t] * bv[g * 9 + t];
            cf[9] = d;
        }
    }
    __syncthreads();

    // ---- Phase 4: 3x3 stride-2 conv (512-thread strided, register-light) ----
    float cc[9];
#pragma unroll
    for (int j = 0; j < 9; ++j) cc[j] = cf[j];
    const float dd = cf[9];
    float* __restrict__ op = out + (size_t)bg * NP;

    for (int task = tid; task < NTASK; task += BLK) {
        const int ph = task / NCH;
        const int t = task - ph * NCH;
        const int r0 = 2 * ph - 1;
        float L[3][9];
#pragma unroll
        for (int kr = 0; kr < 3; ++kr) {
            const int r = r0 + kr;
            if (r < 0) {
#pragma unroll
                for (int j = 0; j < 9; ++j) L[kr][j] = 0.f;
            } else {
                load_row9(xp + r * WW, t, L[kr]);
            }
        }
        float o[4];
#pragma unroll
        for (int u = 0; u < 4; ++u) {
            float s = dd;
#pragma unroll
            for (int kh = 0; kh < 3; ++kh)
#pragma unroll
                for (int kw = 0; kw < 3; ++kw)
                    s += cc[3 * kh + kw] * L[kh][2 * u + kw];
            o[u] = s;
        }
        *reinterpret_cast<float4*>(op + ph * PSD + 4 * t) =
            make_float4(o[0], o[1], o[2], o[3]);
    }
}

extern "C" void kernel_launch(void* const* d_in, const int* in_sizes, int n_in,
                              void* d_out, int out_size, void* d_ws, size_t ws_size,
                              hipStream_t stream) {
    const float* x = (const float*)d_in[0];
    const float* Wq = (const float*)d_in[1];
    const float* bq = (const float*)d_in[2];
    const float* Wk = (const float*)d_in[3];
    const float* bk = (const float*)d_in[4];
    const float* Wv = (const float*)d_in[5];
    const float* bv = (const float*)d_in[6];
    const float* Wo = (const float*)d_in[7];
    const float* bo = (const float*)d_in[8];
    float* out = (float*)d_out;

    scann_k<<<NBG, BLK, 0, stream>>>(x, Wq, bq, Wk, bk, Wv, bv, Wo, bo, out);
}